// Round 1
// baseline (894.692 us; speedup 1.0000x reference)
//
#include <hip/hip_runtime.h>

// Problem: imgs (8,3,1024,1024) fp32, z (1e6,2) fp32 -> out (8,2) fp32.
// Per point: bilinear-gradient gather of 2x2 neighborhood in all 24 planes,
// reduced to 16 scalars. Memory-gather bound.

#define NYX 1024
#define BATCH 8
#define CH 3

__global__ void zero_out_kernel(float* __restrict__ out) {
    int i = threadIdx.x;
    if (i < 16) out[i] = 0.0f;
}

__global__ __launch_bounds__(256) void interp_grad_kernel(
    const float* __restrict__ imgs, const float* __restrict__ z,
    float* __restrict__ out, int npts)
{
    int p = blockIdx.x * blockDim.x + threadIdx.x;

    float acc0[BATCH];
    float acc1[BATCH];
#pragma unroll
    for (int b = 0; b < BATCH; ++b) { acc0[b] = 0.0f; acc1[b] = 0.0f; }

    if (p < npts) {
        float zy = z[2 * p + 0];
        float zx = z[2 * p + 1];
        float x0y = zy * (float)(NYX - 1);
        float x0x = zx * (float)(NYX - 1);
        bool oob = (x0y < 0.0f) || (x0y > (float)(NYX - 1)) ||
                   (x0x < 0.0f) || (x0x > (float)(NYX - 1));
        if (!oob) {
            int yg = (int)floorf(x0y);
            int xg = (int)floorf(x0x);
            // defensive clamp: only affects the measure-zero x0==1023.0 case
            yg = min(yg, NYX - 2);
            xg = min(xg, NYX - 2);
            float fy = (float)yg - x0y;   // in (-1, 0]
            float fx = (float)xg - x0x;

            const float* base = imgs + (size_t)yg * NYX + xg;
#pragma unroll
            for (int b = 0; b < BATCH; ++b) {
#pragma unroll
                for (int c = 0; c < CH; ++c) {
                    const float* pl = base + (size_t)(b * CH + c) * (size_t)(NYX * NYX);
                    float g00 = pl[0];
                    float g01 = pl[1];
                    float g10 = pl[NYX];
                    float g11 = pl[NYX + 1];
                    float a1 = g10 - g00;
                    float a2 = g11 - g01;
                    float a3 = g01 - g00;
                    float d  = a1 - a2;
                    acc0[b] += d * fx + a1;
                    acc1[b] += d * fy + a3;
                }
            }
        }
    }

    // wave-64 shuffle reduction of the 16 accumulators
#pragma unroll
    for (int b = 0; b < BATCH; ++b) {
#pragma unroll
        for (int off = 32; off > 0; off >>= 1) {
            acc0[b] += __shfl_down(acc0[b], off, 64);
            acc1[b] += __shfl_down(acc1[b], off, 64);
        }
    }

    __shared__ float sred[4][16];
    int lane = threadIdx.x & 63;
    int wave = threadIdx.x >> 6;
    if (lane == 0) {
#pragma unroll
        for (int b = 0; b < BATCH; ++b) {
            sred[wave][2 * b + 0] = acc0[b];
            sred[wave][2 * b + 1] = acc1[b];
        }
    }
    __syncthreads();
    if (threadIdx.x < 16) {
        float s = sred[0][threadIdx.x] + sred[1][threadIdx.x] +
                  sred[2][threadIdx.x] + sred[3][threadIdx.x];
        atomicAdd(&out[threadIdx.x], s);
    }
}

extern "C" void kernel_launch(void* const* d_in, const int* in_sizes, int n_in,
                              void* d_out, int out_size, void* d_ws, size_t ws_size,
                              hipStream_t stream) {
    const float* imgs = (const float*)d_in[0];
    const float* z    = (const float*)d_in[1];
    float* out        = (float*)d_out;
    int npts = in_sizes[1] / 2;

    zero_out_kernel<<<1, 64, 0, stream>>>(out);
    int blocks = (npts + 255) / 256;
    interp_grad_kernel<<<blocks, 256, 0, stream>>>(imgs, z, out, npts);
}

// Round 2
// 618.101 us; speedup vs baseline: 1.4475x; 1.4475x over previous
//
#include <hip/hip_runtime.h>

// imgs (8,3,1024,1024) fp32, z (1e6,2) fp32 -> out (8,2) fp32.
// Strategy: counting-sort points into 32x32-pixel spatial bins, then gather
// sorted points so each block's 2x2x24-plane footprint stays L1/L2 resident.

#define NYX 1024
#define BATCH 8
#define CH 3
#define BIN_SHIFT 5                    // 32-pixel bins
#define NBIN_SIDE (NYX >> BIN_SHIFT)   // 32
#define NBINS (NBIN_SIDE * NBIN_SIDE)  // 1024

// ws layout (bytes):
//   [0]      u32 counts[NBINS]
//   [4096]   u32 offsets[NBINS+1]
//   [12288]  u32 cursors[NBINS]
//   [16384]  float4 pts[npts]   (x=pixel offset bits, y=fx, z=fy, w=unused)
#define WS_COUNTS 0
#define WS_OFFS   4096
#define WS_CURS   12288
#define WS_PTS    16384

__device__ __forceinline__ bool point_setup(float zy, float zx,
                                            int& yg, int& xg,
                                            float& fy, float& fx) {
    float x0y = zy * (float)(NYX - 1);
    float x0x = zx * (float)(NYX - 1);
    bool oob = (x0y < 0.0f) || (x0y > (float)(NYX - 1)) ||
               (x0x < 0.0f) || (x0x > (float)(NYX - 1));
    if (oob) return false;
    yg = min((int)floorf(x0y), NYX - 2);
    xg = min((int)floorf(x0x), NYX - 2);
    fy = (float)yg - x0y;
    fx = (float)xg - x0x;
    return true;
}

__global__ void zero_meta_kernel(unsigned* __restrict__ counts,
                                 float* __restrict__ out) {
    int t = threadIdx.x;
    counts[t] = 0u;
    if (t < 16) out[t] = 0.0f;
}

__global__ __launch_bounds__(256) void hist_kernel(
    const float* __restrict__ z, unsigned* __restrict__ counts, int npts)
{
    int p = blockIdx.x * blockDim.x + threadIdx.x;
    if (p >= npts) return;
    float2 zz = ((const float2*)z)[p];
    int yg, xg; float fy, fx;
    if (!point_setup(zz.x, zz.y, yg, xg, fy, fx)) return;
    int bin = ((yg >> BIN_SHIFT) << 5) | (xg >> BIN_SHIFT);
    atomicAdd(&counts[bin], 1u);
}

__global__ __launch_bounds__(NBINS) void scan_kernel(
    const unsigned* __restrict__ counts,
    unsigned* __restrict__ offsets, unsigned* __restrict__ cursors)
{
    __shared__ unsigned tmp[NBINS];
    int t = threadIdx.x;
    unsigned c = counts[t];
    unsigned v = c;
    tmp[t] = v;
    __syncthreads();
#pragma unroll
    for (int off = 1; off < NBINS; off <<= 1) {
        unsigned add = (t >= off) ? tmp[t - off] : 0u;
        __syncthreads();
        v += add;
        tmp[t] = v;
        __syncthreads();
    }
    unsigned excl = v - c;
    offsets[t] = excl;
    cursors[t] = excl;
    if (t == NBINS - 1) offsets[NBINS] = v;
}

__global__ __launch_bounds__(256) void scatter_kernel(
    const float* __restrict__ z, unsigned* __restrict__ cursors,
    float4* __restrict__ pts, int npts)
{
    int p = blockIdx.x * blockDim.x + threadIdx.x;
    if (p >= npts) return;
    float2 zz = ((const float2*)z)[p];
    int yg, xg; float fy, fx;
    if (!point_setup(zz.x, zz.y, yg, xg, fy, fx)) return;
    int bin = ((yg >> BIN_SHIFT) << 5) | (xg >> BIN_SHIFT);
    unsigned pos = atomicAdd(&cursors[bin], 1u);
    pts[pos] = make_float4(__uint_as_float((unsigned)(yg * NYX + xg)), fx, fy, 0.0f);
}

__global__ __launch_bounds__(256) void gather_sorted_kernel(
    const float* __restrict__ imgs, const float4* __restrict__ pts,
    const unsigned* __restrict__ offsets, float* __restrict__ out)
{
    // bijective XCD-chunk swizzle: XCD x (bid%8) gets a contiguous block range
    unsigned nb = gridDim.x, q = nb >> 3, r = nb & 7;
    unsigned x = blockIdx.x & 7, j = blockIdx.x >> 3;
    unsigned sb = x * q + min(x, r) + j;

    unsigned total = offsets[NBINS];
    unsigned p = sb * blockDim.x + threadIdx.x;

    float acc0[BATCH];
    float acc1[BATCH];
#pragma unroll
    for (int b = 0; b < BATCH; ++b) { acc0[b] = 0.0f; acc1[b] = 0.0f; }

    if (p < total) {
        float4 pt = pts[p];
        unsigned offs = __float_as_uint(pt.x);
        float fx = pt.y, fy = pt.z;
        const float* base = imgs + offs;
#pragma unroll
        for (int b = 0; b < BATCH; ++b) {
#pragma unroll
            for (int c = 0; c < CH; ++c) {
                const float* pl = base + (size_t)(b * CH + c) * (size_t)(NYX * NYX);
                float g00 = pl[0];
                float g01 = pl[1];
                float g10 = pl[NYX];
                float g11 = pl[NYX + 1];
                float a1 = g10 - g00;
                float a2 = g11 - g01;
                float a3 = g01 - g00;
                float d  = a1 - a2;
                acc0[b] += d * fx + a1;
                acc1[b] += d * fy + a3;
            }
        }
    }

#pragma unroll
    for (int b = 0; b < BATCH; ++b) {
#pragma unroll
        for (int off = 32; off > 0; off >>= 1) {
            acc0[b] += __shfl_down(acc0[b], off, 64);
            acc1[b] += __shfl_down(acc1[b], off, 64);
        }
    }

    __shared__ float sred[4][16];
    int lane = threadIdx.x & 63;
    int wave = threadIdx.x >> 6;
    if (lane == 0) {
#pragma unroll
        for (int b = 0; b < BATCH; ++b) {
            sred[wave][2 * b + 0] = acc0[b];
            sred[wave][2 * b + 1] = acc1[b];
        }
    }
    __syncthreads();
    if (threadIdx.x < 16) {
        float s = sred[0][threadIdx.x] + sred[1][threadIdx.x] +
                  sred[2][threadIdx.x] + sred[3][threadIdx.x];
        atomicAdd(&out[threadIdx.x], s);
    }
}

// ---- fallback (round-1 unsorted path) if ws is too small ----
__global__ void zero_out_kernel(float* __restrict__ out) {
    int i = threadIdx.x;
    if (i < 16) out[i] = 0.0f;
}

__global__ __launch_bounds__(256) void interp_grad_kernel(
    const float* __restrict__ imgs, const float* __restrict__ z,
    float* __restrict__ out, int npts)
{
    int p = blockIdx.x * blockDim.x + threadIdx.x;
    float acc0[BATCH];
    float acc1[BATCH];
#pragma unroll
    for (int b = 0; b < BATCH; ++b) { acc0[b] = 0.0f; acc1[b] = 0.0f; }
    if (p < npts) {
        float2 zz = ((const float2*)z)[p];
        int yg, xg; float fy, fx;
        if (point_setup(zz.x, zz.y, yg, xg, fy, fx)) {
            const float* base = imgs + (size_t)yg * NYX + xg;
#pragma unroll
            for (int b = 0; b < BATCH; ++b) {
#pragma unroll
                for (int c = 0; c < CH; ++c) {
                    const float* pl = base + (size_t)(b * CH + c) * (size_t)(NYX * NYX);
                    float g00 = pl[0];
                    float g01 = pl[1];
                    float g10 = pl[NYX];
                    float g11 = pl[NYX + 1];
                    float a1 = g10 - g00;
                    float a2 = g11 - g01;
                    float a3 = g01 - g00;
                    float d  = a1 - a2;
                    acc0[b] += d * fx + a1;
                    acc1[b] += d * fy + a3;
                }
            }
        }
    }
#pragma unroll
    for (int b = 0; b < BATCH; ++b) {
#pragma unroll
        for (int off = 32; off > 0; off >>= 1) {
            acc0[b] += __shfl_down(acc0[b], off, 64);
            acc1[b] += __shfl_down(acc1[b], off, 64);
        }
    }
    __shared__ float sred[4][16];
    int lane = threadIdx.x & 63;
    int wave = threadIdx.x >> 6;
    if (lane == 0) {
#pragma unroll
        for (int b = 0; b < BATCH; ++b) {
            sred[wave][2 * b + 0] = acc0[b];
            sred[wave][2 * b + 1] = acc1[b];
        }
    }
    __syncthreads();
    if (threadIdx.x < 16) {
        float s = sred[0][threadIdx.x] + sred[1][threadIdx.x] +
                  sred[2][threadIdx.x] + sred[3][threadIdx.x];
        atomicAdd(&out[threadIdx.x], s);
    }
}

extern "C" void kernel_launch(void* const* d_in, const int* in_sizes, int n_in,
                              void* d_out, int out_size, void* d_ws, size_t ws_size,
                              hipStream_t stream) {
    const float* imgs = (const float*)d_in[0];
    const float* z    = (const float*)d_in[1];
    float* out        = (float*)d_out;
    int npts = in_sizes[1] / 2;

    size_t ws_need = (size_t)WS_PTS + (size_t)npts * sizeof(float4);
    int blocks = (npts + 255) / 256;

    if (ws_size < ws_need) {
        // fallback: unsorted gather
        zero_out_kernel<<<1, 64, 0, stream>>>(out);
        interp_grad_kernel<<<blocks, 256, 0, stream>>>(imgs, z, out, npts);
        return;
    }

    char* ws = (char*)d_ws;
    unsigned* counts  = (unsigned*)(ws + WS_COUNTS);
    unsigned* offsets = (unsigned*)(ws + WS_OFFS);
    unsigned* cursors = (unsigned*)(ws + WS_CURS);
    float4*   pts     = (float4*)(ws + WS_PTS);

    zero_meta_kernel<<<1, NBINS, 0, stream>>>(counts, out);
    hist_kernel<<<blocks, 256, 0, stream>>>(z, counts, npts);
    scan_kernel<<<1, NBINS, 0, stream>>>(counts, offsets, cursors);
    scatter_kernel<<<blocks, 256, 0, stream>>>(z, cursors, pts, npts);
    gather_sorted_kernel<<<blocks, 256, 0, stream>>>(imgs, pts, offsets, out);
}

// Round 4
// 327.680 us; speedup vs baseline: 2.7304x; 1.8863x over previous
//
#include <hip/hip_runtime.h>

// imgs (8,3,1024,1024) fp32, z (1e6,2) fp32 -> out (8,2) fp32.
// Strategy: counting-sort points into 32x32-pixel spatial bins, then gather
// sorted points so each block's 2x2x24-plane footprint stays L1/L2 resident.
// R3: bin counters/cursors padded to one 128B cache line each (atomic serialization fix).
// R4: fix ws overlap — offsets[NBINS] was colliding with pts[0] (WS_PTS 266240->270336).

#define NYX 1024
#define BATCH 8
#define CH 3
#define BIN_SHIFT 5                    // 32-pixel bins
#define NBIN_SIDE (NYX >> BIN_SHIFT)   // 32
#define NBINS (NBIN_SIDE * NBIN_SIDE)  // 1024
#define PAD 32                         // u32 stride per bin counter = 128 B line

// ws layout (bytes):
//   [0]       u32 counts[NBINS*PAD]    (128 KB, line-padded)
//   [131072]  u32 cursors[NBINS*PAD]   (128 KB, line-padded)
//   [262144]  u32 offsets[NBINS+1]     (4100 B, given an 8 KB slot)
//   [270336]  float4 pts[npts]
#define WS_COUNTS 0
#define WS_CURS   131072
#define WS_OFFS   262144
#define WS_PTS    270336

__device__ __forceinline__ bool point_setup(float zy, float zx,
                                            int& yg, int& xg,
                                            float& fy, float& fx) {
    float x0y = zy * (float)(NYX - 1);
    float x0x = zx * (float)(NYX - 1);
    bool oob = (x0y < 0.0f) || (x0y > (float)(NYX - 1)) ||
               (x0x < 0.0f) || (x0x > (float)(NYX - 1));
    if (oob) return false;
    yg = min((int)floorf(x0y), NYX - 2);
    xg = min((int)floorf(x0x), NYX - 2);
    fy = (float)yg - x0y;
    fx = (float)xg - x0x;
    return true;
}

__global__ __launch_bounds__(256) void zero_meta_kernel(
    unsigned* __restrict__ counts, float* __restrict__ out)
{
    int t = blockIdx.x * blockDim.x + threadIdx.x;
    if (t < NBINS * PAD) counts[t] = 0u;   // counts only; cursors set by scan
    if (t < 16) out[t] = 0.0f;
}

__global__ __launch_bounds__(256) void hist_kernel(
    const float* __restrict__ z, unsigned* __restrict__ counts, int npts)
{
    int p = blockIdx.x * blockDim.x + threadIdx.x;
    if (p >= npts) return;
    float2 zz = ((const float2*)z)[p];
    int yg, xg; float fy, fx;
    if (!point_setup(zz.x, zz.y, yg, xg, fy, fx)) return;
    int bin = ((yg >> BIN_SHIFT) << 5) | (xg >> BIN_SHIFT);
    atomicAdd(&counts[bin * PAD], 1u);
}

__global__ __launch_bounds__(NBINS) void scan_kernel(
    const unsigned* __restrict__ counts,
    unsigned* __restrict__ offsets, unsigned* __restrict__ cursors)
{
    __shared__ unsigned tmp[NBINS];
    int t = threadIdx.x;
    unsigned c = counts[t * PAD];
    unsigned v = c;
    tmp[t] = v;
    __syncthreads();
#pragma unroll
    for (int off = 1; off < NBINS; off <<= 1) {
        unsigned add = (t >= off) ? tmp[t - off] : 0u;
        __syncthreads();
        v += add;
        tmp[t] = v;
        __syncthreads();
    }
    unsigned excl = v - c;
    offsets[t] = excl;
    cursors[t * PAD] = excl;
    if (t == NBINS - 1) offsets[NBINS] = v;
}

__global__ __launch_bounds__(256) void scatter_kernel(
    const float* __restrict__ z, unsigned* __restrict__ cursors,
    float4* __restrict__ pts, int npts)
{
    int p = blockIdx.x * blockDim.x + threadIdx.x;
    if (p >= npts) return;
    float2 zz = ((const float2*)z)[p];
    int yg, xg; float fy, fx;
    if (!point_setup(zz.x, zz.y, yg, xg, fy, fx)) return;
    int bin = ((yg >> BIN_SHIFT) << 5) | (xg >> BIN_SHIFT);
    unsigned pos = atomicAdd(&cursors[bin * PAD], 1u);
    pts[pos] = make_float4(__uint_as_float((unsigned)(yg * NYX + xg)), fx, fy, 0.0f);
}

__global__ __launch_bounds__(256) void gather_sorted_kernel(
    const float* __restrict__ imgs, const float4* __restrict__ pts,
    const unsigned* __restrict__ offsets, float* __restrict__ out)
{
    // bijective XCD-chunk swizzle: XCD x (bid%8) gets a contiguous block range
    unsigned nb = gridDim.x, q = nb >> 3, r = nb & 7;
    unsigned x = blockIdx.x & 7, j = blockIdx.x >> 3;
    unsigned sb = x * q + min(x, r) + j;

    unsigned total = offsets[NBINS];
    unsigned p = sb * blockDim.x + threadIdx.x;

    float acc0[BATCH];
    float acc1[BATCH];
#pragma unroll
    for (int b = 0; b < BATCH; ++b) { acc0[b] = 0.0f; acc1[b] = 0.0f; }

    if (p < total) {
        float4 pt = pts[p];
        unsigned offs = __float_as_uint(pt.x);
        float fx = pt.y, fy = pt.z;
        const float* base = imgs + offs;
#pragma unroll
        for (int b = 0; b < BATCH; ++b) {
#pragma unroll
            for (int c = 0; c < CH; ++c) {
                const float* pl = base + (size_t)(b * CH + c) * (size_t)(NYX * NYX);
                float g00 = pl[0];
                float g01 = pl[1];
                float g10 = pl[NYX];
                float g11 = pl[NYX + 1];
                float a1 = g10 - g00;
                float a2 = g11 - g01;
                float a3 = g01 - g00;
                float d  = a1 - a2;
                acc0[b] += d * fx + a1;
                acc1[b] += d * fy + a3;
            }
        }
    }

#pragma unroll
    for (int b = 0; b < BATCH; ++b) {
#pragma unroll
        for (int off = 32; off > 0; off >>= 1) {
            acc0[b] += __shfl_down(acc0[b], off, 64);
            acc1[b] += __shfl_down(acc1[b], off, 64);
        }
    }

    __shared__ float sred[4][16];
    int lane = threadIdx.x & 63;
    int wave = threadIdx.x >> 6;
    if (lane == 0) {
#pragma unroll
        for (int b = 0; b < BATCH; ++b) {
            sred[wave][2 * b + 0] = acc0[b];
            sred[wave][2 * b + 1] = acc1[b];
        }
    }
    __syncthreads();
    if (threadIdx.x < 16) {
        float s = sred[0][threadIdx.x] + sred[1][threadIdx.x] +
                  sred[2][threadIdx.x] + sred[3][threadIdx.x];
        atomicAdd(&out[threadIdx.x], s);
    }
}

// ---- fallback (round-1 unsorted path) if ws is too small ----
__global__ void zero_out_kernel(float* __restrict__ out) {
    int i = threadIdx.x;
    if (i < 16) out[i] = 0.0f;
}

__global__ __launch_bounds__(256) void interp_grad_kernel(
    const float* __restrict__ imgs, const float* __restrict__ z,
    float* __restrict__ out, int npts)
{
    int p = blockIdx.x * blockDim.x + threadIdx.x;
    float acc0[BATCH];
    float acc1[BATCH];
#pragma unroll
    for (int b = 0; b < BATCH; ++b) { acc0[b] = 0.0f; acc1[b] = 0.0f; }
    if (p < npts) {
        float2 zz = ((const float2*)z)[p];
        int yg, xg; float fy, fx;
        if (point_setup(zz.x, zz.y, yg, xg, fy, fx)) {
            const float* base = imgs + (size_t)yg * NYX + xg;
#pragma unroll
            for (int b = 0; b < BATCH; ++b) {
#pragma unroll
                for (int c = 0; c < CH; ++c) {
                    const float* pl = base + (size_t)(b * CH + c) * (size_t)(NYX * NYX);
                    float g00 = pl[0];
                    float g01 = pl[1];
                    float g10 = pl[NYX];
                    float g11 = pl[NYX + 1];
                    float a1 = g10 - g00;
                    float a2 = g11 - g01;
                    float a3 = g01 - g00;
                    float d  = a1 - a2;
                    acc0[b] += d * fx + a1;
                    acc1[b] += d * fy + a3;
                }
            }
        }
    }
#pragma unroll
    for (int b = 0; b < BATCH; ++b) {
#pragma unroll
        for (int off = 32; off > 0; off >>= 1) {
            acc0[b] += __shfl_down(acc0[b], off, 64);
            acc1[b] += __shfl_down(acc1[b], off, 64);
        }
    }
    __shared__ float sred[4][16];
    int lane = threadIdx.x & 63;
    int wave = threadIdx.x >> 6;
    if (lane == 0) {
#pragma unroll
        for (int b = 0; b < BATCH; ++b) {
            sred[wave][2 * b + 0] = acc0[b];
            sred[wave][2 * b + 1] = acc1[b];
        }
    }
    __syncthreads();
    if (threadIdx.x < 16) {
        float s = sred[0][threadIdx.x] + sred[1][threadIdx.x] +
                  sred[2][threadIdx.x] + sred[3][threadIdx.x];
        atomicAdd(&out[threadIdx.x], s);
    }
}

extern "C" void kernel_launch(void* const* d_in, const int* in_sizes, int n_in,
                              void* d_out, int out_size, void* d_ws, size_t ws_size,
                              hipStream_t stream) {
    const float* imgs = (const float*)d_in[0];
    const float* z    = (const float*)d_in[1];
    float* out        = (float*)d_out;
    int npts = in_sizes[1] / 2;

    size_t ws_need = (size_t)WS_PTS + (size_t)npts * sizeof(float4);
    int blocks = (npts + 255) / 256;

    if (ws_size < ws_need) {
        // fallback: unsorted gather
        zero_out_kernel<<<1, 64, 0, stream>>>(out);
        interp_grad_kernel<<<blocks, 256, 0, stream>>>(imgs, z, out, npts);
        return;
    }

    char* ws = (char*)d_ws;
    unsigned* counts  = (unsigned*)(ws + WS_COUNTS);
    unsigned* cursors = (unsigned*)(ws + WS_CURS);
    unsigned* offsets = (unsigned*)(ws + WS_OFFS);
    float4*   pts     = (float4*)(ws + WS_PTS);

    zero_meta_kernel<<<(NBINS * PAD + 255) / 256, 256, 0, stream>>>(counts, out);
    hist_kernel<<<blocks, 256, 0, stream>>>(z, counts, npts);
    scan_kernel<<<1, NBINS, 0, stream>>>(counts, offsets, cursors);
    scatter_kernel<<<blocks, 256, 0, stream>>>(z, cursors, pts, npts);
    gather_sorted_kernel<<<blocks, 256, 0, stream>>>(imgs, pts, offsets, out);
}